// Round 1
// baseline (497.834 us; speedup 1.0000x reference)
//
#include <hip/hip_runtime.h>

#define N_NEURON 500000
#define N_EDGE   10000000

// Reference constants: DT=0.1, TAO_D=2.0, TAO_R=10.0
// LAMDA_D = DT/TAO_D = 0.05 ; LAMDA_R = DT/TAO_R = 0.01
#define DT_C      0.1f
#define LAMDA_D_C 0.05f
#define LAMDA_R_C 0.01f
#define INV_TAO_D 0.5f   // 1/2.0

// Kernel 1: per-neuron pointwise update.
//   Iback_new = Iback + dt_over_tau*(noise - Iback)
//   Ieff      = Iback_new / sqrt_coeff * sig + mu      -> written to out
//   s_new     = s + LAMDA_R*(-s + spike/TAO_D)
//   r_new     = r - LAMDA_D*r + DT*s_new               -> written to ws
__global__ void neuron_update(const float* __restrict__ Iback,
                              const float* __restrict__ spike,
                              const float* __restrict__ s,
                              const float* __restrict__ r,
                              const float* __restrict__ noise,
                              const float* __restrict__ dt_over_tau,
                              const float* __restrict__ sqrt_coeff,
                              const float* __restrict__ sig,
                              const float* __restrict__ mu,
                              float* __restrict__ r_new,
                              float* __restrict__ out,
                              int n) {
    const float dtau = dt_over_tau[0];
    const float sq   = sqrt_coeff[0];
    const float sg   = sig[0];
    const float m    = mu[0];
    for (int i = blockIdx.x * blockDim.x + threadIdx.x; i < n;
         i += gridDim.x * blockDim.x) {
        float ib  = Iback[i];
        float ibn = ib + dtau * (noise[i] - ib);
        float ieff = ibn / sq * sg + m;
        float sv  = s[i];
        float sn  = sv + LAMDA_R_C * (-sv + spike[i] * INV_TAO_D);
        float rv  = r[i];
        float rn  = rv - LAMDA_D_C * rv + DT_C * sn;
        r_new[i] = rn;
        out[i]   = ieff;  // initializes output with Ieff; edges accumulate on top
    }
}

// Kernel 2: COO scatter-add. edges flat layout: [0,N_EDGE)=post, [N_EDGE,2N)=pre.
__global__ void edge_scatter(const float* __restrict__ weight,
                             const int* __restrict__ post,
                             const int* __restrict__ pre,
                             const float* __restrict__ r_new,
                             float* __restrict__ out,
                             int n_edge) {
    for (int e = blockIdx.x * blockDim.x + threadIdx.x; e < n_edge;
         e += gridDim.x * blockDim.x) {
        int p = post[e];
        int q = pre[e];
        atomicAdd(&out[p], weight[e] * r_new[q]);
    }
}

extern "C" void kernel_launch(void* const* d_in, const int* in_sizes, int n_in,
                              void* d_out, int out_size, void* d_ws, size_t ws_size,
                              hipStream_t stream) {
    const float* weight      = (const float*)d_in[0];
    const int*   edges       = (const int*)d_in[1];   // (2, N_EDGE) flat
    const float* Iback       = (const float*)d_in[2];
    const float* spike       = (const float*)d_in[3];
    const float* s           = (const float*)d_in[4];
    const float* r           = (const float*)d_in[5];
    const float* noise       = (const float*)d_in[6];
    const float* dt_over_tau = (const float*)d_in[7];
    const float* sqrt_coeff  = (const float*)d_in[8];
    const float* sig         = (const float*)d_in[9];
    const float* mu          = (const float*)d_in[10];

    float* out   = (float*)d_out;
    float* r_new = (float*)d_ws;      // N_NEURON floats = 2 MB scratch

    const int n_edge = in_sizes[0];   // 10M
    const int n      = out_size;      // 500k

    // Pointwise neuron update: memory-trivial (~12 MB)
    {
        int block = 256;
        int grid  = (n + block - 1) / block;  // ~1954 blocks
        neuron_update<<<grid, block, 0, stream>>>(
            Iback, spike, s, r, noise, dt_over_tau, sqrt_coeff, sig, mu,
            r_new, out, n);
    }

    // Edge scatter: grid-stride, ~2048 blocks (G11 memory-bound sizing)
    {
        int block = 256;
        int grid  = 4096;
        edge_scatter<<<grid, block, 0, stream>>>(
            weight, edges /*post*/, edges + n_edge /*pre*/, r_new, out, n_edge);
    }
}

// Round 2
// 220.307 us; speedup vs baseline: 2.2597x; 2.2597x over previous
//
#include <hip/hip_runtime.h>

#define N_NEURON 500000
#define N_EDGE   10000000

// DT=0.1, TAO_D=2.0, TAO_R=10.0
#define DT_C      0.1f
#define LAMDA_D_C 0.05f
#define LAMDA_R_C 0.01f
#define INV_TAO_D 0.5f

// ---- binning geometry ----
#define BUCKET_SHIFT 11
#define BUCKET_W     (1 << BUCKET_SHIFT)                          // 2048 neurons/bucket
#define NBUCKET      ((N_NEURON + BUCKET_W - 1) >> BUCKET_SHIFT)  // 245
#define CAP          46080   // per-bucket record capacity (mean load 40.8k, +4sigma ~ 41.6k)

#define P1_BLOCK 512
#define P1_EPT   32
#define P1_CHUNK (P1_BLOCK * P1_EPT)  // 16384 edges/block

// ws layout
#define WS_RNEW_OFF    0
#define WS_CURSOR_OFF  (2u * 1024u * 1024u)            // 2 MB (r_new = 2,000,000 B)
#define WS_REC_OFF     (WS_CURSOR_OFF + 4096u)
#define WS_NEEDED      ((size_t)WS_REC_OFF + (size_t)NBUCKET * CAP * 8u)

// Kernel 1: per-neuron pointwise update. Writes r_new to ws, Ieff to out
// (this initializes out, which the harness poisons to 0xAA).
__global__ void neuron_update(const float* __restrict__ Iback,
                              const float* __restrict__ spike,
                              const float* __restrict__ s,
                              const float* __restrict__ r,
                              const float* __restrict__ noise,
                              const float* __restrict__ dt_over_tau,
                              const float* __restrict__ sqrt_coeff,
                              const float* __restrict__ sig,
                              const float* __restrict__ mu,
                              float* __restrict__ r_new,
                              float* __restrict__ out,
                              int n) {
    const float dtau = dt_over_tau[0];
    const float sq   = sqrt_coeff[0];
    const float sg   = sig[0];
    const float m    = mu[0];
    for (int i = blockIdx.x * blockDim.x + threadIdx.x; i < n;
         i += gridDim.x * blockDim.x) {
        float ib  = Iback[i];
        float ibn = ib + dtau * (noise[i] - ib);
        float ieff = ibn / sq * sg + m;
        float sv  = s[i];
        float sn  = sv + LAMDA_R_C * (-sv + spike[i] * INV_TAO_D);
        float rv  = r[i];
        float rn  = rv - LAMDA_D_C * rv + DT_C * sn;
        r_new[i] = rn;
        out[i]   = ieff;
    }
}

// Pass 1: partition edges into per-bucket record lists (post, w*r_new[pre]).
// Global atomics: one per (block, bucket) for space reservation (~150k total
// vs 10M in the naive scatter). Records are written as dense 8B uint2.
__global__ __launch_bounds__(P1_BLOCK) void edge_bin(
        const float* __restrict__ weight,
        const int*   __restrict__ post_arr,
        const int*   __restrict__ pre_arr,
        const float* __restrict__ r_new,
        uint2*       __restrict__ records,
        unsigned*    __restrict__ cursor,
        float*       __restrict__ out,
        int n_edge) {
    __shared__ unsigned cnt[NBUCKET];
    __shared__ unsigned base[NBUCKET];
    const int t = threadIdx.x;
    for (int i = t; i < NBUCKET; i += P1_BLOCK) cnt[i] = 0;
    __syncthreads();

    const int chunk0 = blockIdx.x * P1_CHUNK;
    unsigned meta[P1_EPT];  // (bucket << 18) | local_slot ; static-indexed only

    // Phase A: histogram + per-record local slot assignment (LDS atomics)
    #pragma unroll
    for (int k = 0; k < P1_EPT / 4; ++k) {
        const int e = chunk0 + k * (P1_BLOCK * 4) + t * 4;
        if (e < n_edge) {
            const int4 p4 = *reinterpret_cast<const int4*>(post_arr + e);
            const int ps[4] = {p4.x, p4.y, p4.z, p4.w};
            #pragma unroll
            for (int j = 0; j < 4; ++j) {
                const unsigned b = ((unsigned)ps[j]) >> BUCKET_SHIFT;
                const unsigned l = atomicAdd(&cnt[b], 1u);
                meta[k * 4 + j] = (b << 18) | l;
            }
        } else {
            #pragma unroll
            for (int j = 0; j < 4; ++j) meta[k * 4 + j] = 0xFFFFFFFFu;
        }
    }
    __syncthreads();

    // Phase B: reserve global space, one atomic per (block,bucket)
    for (int i = t; i < NBUCKET; i += P1_BLOCK)
        base[i] = atomicAdd(&cursor[i], cnt[i]);
    __syncthreads();

    // Phase C: re-load edges (L2-hot), compute v, store record
    #pragma unroll
    for (int k = 0; k < P1_EPT / 4; ++k) {
        const int e = chunk0 + k * (P1_BLOCK * 4) + t * 4;
        if (e < n_edge) {
            const int4   p4 = *reinterpret_cast<const int4*>(post_arr + e);
            const int4   q4 = *reinterpret_cast<const int4*>(pre_arr + e);
            const float4 w4 = *reinterpret_cast<const float4*>(weight + e);
            const int   ps[4] = {p4.x, p4.y, p4.z, p4.w};
            const int   qs[4] = {q4.x, q4.y, q4.z, q4.w};
            const float ws[4] = {w4.x, w4.y, w4.z, w4.w};
            #pragma unroll
            for (int j = 0; j < 4; ++j) {
                const unsigned m   = meta[k * 4 + j];
                const unsigned b   = m >> 18;
                const unsigned idx = base[b] + (m & 0x3FFFFu);
                const float    v   = ws[j] * r_new[qs[j]];
                if (idx < CAP) {
                    records[(size_t)b * CAP + idx] =
                        make_uint2((unsigned)ps[j], __float_as_uint(v));
                } else {
                    atomicAdd(&out[ps[j]], v);  // overflow fallback (never expected)
                }
            }
        }
    }
}

// Pass 2: one block per bucket. LDS accumulate (ds_add_f32), then one
// non-atomic += pass into out (out already holds Ieff + any spills).
__global__ __launch_bounds__(1024) void bucket_reduce(
        const uint2*    __restrict__ records,
        const unsigned* __restrict__ cursor,
        float*          __restrict__ out,
        int n) {
    __shared__ float acc[BUCKET_W];
    const int b = blockIdx.x;
    const int t = threadIdx.x;
    for (int i = t; i < BUCKET_W; i += 1024) acc[i] = 0.f;
    __syncthreads();

    unsigned count = cursor[b];
    if (count > CAP) count = CAP;
    const uint2* list = records + (size_t)b * CAP;
    for (unsigned i = t; i < count; i += 1024) {
        const uint2 rec = list[i];
        atomicAdd(&acc[rec.x & (BUCKET_W - 1)], __uint_as_float(rec.y));
    }
    __syncthreads();

    const int g0 = b << BUCKET_SHIFT;
    for (int i = t; i < BUCKET_W; i += 1024) {
        const int g = g0 + i;
        if (g < n) out[g] += acc[i];
    }
}

// R1 fallback (used only if ws_size can't hold the record store)
__global__ void edge_scatter(const float* __restrict__ weight,
                             const int* __restrict__ post,
                             const int* __restrict__ pre,
                             const float* __restrict__ r_new,
                             float* __restrict__ out,
                             int n_edge) {
    for (int e = blockIdx.x * blockDim.x + threadIdx.x; e < n_edge;
         e += gridDim.x * blockDim.x) {
        atomicAdd(&out[post[e]], weight[e] * r_new[pre[e]]);
    }
}

extern "C" void kernel_launch(void* const* d_in, const int* in_sizes, int n_in,
                              void* d_out, int out_size, void* d_ws, size_t ws_size,
                              hipStream_t stream) {
    const float* weight      = (const float*)d_in[0];
    const int*   edges       = (const int*)d_in[1];   // (2, N_EDGE) flat: post then pre
    const float* Iback       = (const float*)d_in[2];
    const float* spike       = (const float*)d_in[3];
    const float* s           = (const float*)d_in[4];
    const float* r           = (const float*)d_in[5];
    const float* noise       = (const float*)d_in[6];
    const float* dt_over_tau = (const float*)d_in[7];
    const float* sqrt_coeff  = (const float*)d_in[8];
    const float* sig         = (const float*)d_in[9];
    const float* mu          = (const float*)d_in[10];

    float* out = (float*)d_out;
    char*  ws  = (char*)d_ws;

    float*    r_new   = (float*)(ws + WS_RNEW_OFF);
    unsigned* cursor  = (unsigned*)(ws + WS_CURSOR_OFF);
    uint2*    records = (uint2*)(ws + WS_REC_OFF);

    const int n_edge = in_sizes[0];   // 10M
    const int n      = out_size;      // 500k

    // 1) pointwise neuron update; fills out with Ieff
    {
        const int block = 256;
        const int grid  = (n + block - 1) / block;
        neuron_update<<<grid, block, 0, stream>>>(
            Iback, spike, s, r, noise, dt_over_tau, sqrt_coeff, sig, mu,
            r_new, out, n);
    }

    if (ws_size >= WS_NEEDED) {
        // 2) zero bucket cursors (must happen every call; ws not re-poisoned)
        hipMemsetAsync(cursor, 0, NBUCKET * sizeof(unsigned), stream);

        // 3) partition edges into bucket record lists
        {
            const int grid = (n_edge + P1_CHUNK - 1) / P1_CHUNK;  // 611
            edge_bin<<<grid, P1_BLOCK, 0, stream>>>(
                weight, edges, edges + n_edge, r_new, records, cursor, out, n_edge);
        }

        // 4) per-bucket LDS reduction -> out
        bucket_reduce<<<NBUCKET, 1024, 0, stream>>>(records, cursor, out, n);
    } else {
        // fallback: naive device-scope atomic scatter
        edge_scatter<<<4096, 256, 0, stream>>>(
            weight, edges, edges + n_edge, r_new, out, n_edge);
    }
}